// Round 1
// baseline (233.483 us; speedup 1.0000x reference)
//
#include <hip/hip_runtime.h>
#include <hip/hip_bf16.h>

#define B_ 2
#define N_ 4096
#define C_ 32
#define O_ 32
#define NCELLS 27
#define KPAD 28
#define FDIM (KPAD * C_)   // 896

constexpr float SIGMA = 2546.4790894703255f;   // 8/(pi*h^3), h=0.1
constexpr float TH2   = 0.0348215f;            // (0.1 + 0.05*sqrt(3))^2 + margin

// ---------------- K1: prep — coef = data/(invmass*density); W2[f][o] transpose ----------------
__global__ void __launch_bounds__(256) prep_kernel(const float* __restrict__ locs,
                                                   const float* __restrict__ data,
                                                   const float* __restrict__ density,
                                                   const float* __restrict__ weight,
                                                   float* __restrict__ coef,
                                                   float* __restrict__ W2) {
    int t = blockIdx.x * 256 + threadIdx.x;
    if (t < B_ * N_ * C_) {
        int bj = t >> 5;                       // b*N + j   (C_ == 32)
        float im = locs[bj * 4 + 3];           // invmass lives in locs[...,3]
        float de = density[bj];
        coef[t] = data[t] * (1.0f / (im * de));
    } else {
        int u = t - B_ * N_ * C_;
        if (u < FDIM * O_) {
            int o = u & 31;
            int f = u >> 5;
            int k = f >> 5;                    // cell
            int c = f & 31;                    // channel
            W2[u] = (k < NCELLS) ? weight[(o * C_ + c) * NCELLS + k] : 0.0f;
        }
    }
}

// ---------------- K2: main — per-wave query, sparse candidate scan + field accumulation -------
__global__ void __launch_bounds__(256) field_kernel(const float* __restrict__ locs,
                                                    const float* __restrict__ coef,
                                                    float* __restrict__ field) {
    const int wave = threadIdx.x >> 6;
    const int lane = threadIdx.x & 63;
    const int qi   = blockIdx.x * 4 + wave;    // 0..8191
    const int b    = qi >> 12;                 // qi / 4096
    const int i    = qi & (N_ - 1);

    const float4* pos4 = reinterpret_cast<const float4*>(locs) + (size_t)b * N_;
    float4 pq = pos4[i];
    const float xi = pq.x, yi = pq.y, zi = pq.z;

    // per-lane cell constants (k = lane; lanes >= 27 forced to w = 0 via huge nsq)
    const int k = lane;
    const float exf = (float)(k / 9)       - 1.0f;   // dim0 offset sign (meshgrid 'ij')
    const float eyf = (float)((k / 3) % 3) - 1.0f;   // dim1
    const float ezf = (float)(k % 3)       - 1.0f;   // dim2
    const float nsq = (k < NCELLS)
        ? 0.0025f * (exf * exf + eyf * eyf + ezf * ezf)
        : 1e9f;                                      // -> q >= 1 -> w = 0

    const int h     = lane >> 5;       // half: owns cells kbase..kbase+13
    const int kbase = h * 14;
    const int c     = lane & 31;       // owned channel
    const float* coefb = coef + (size_t)b * N_ * C_;

    float acc[14];
#pragma unroll
    for (int t = 0; t < 14; ++t) acc[t] = 0.0f;

    for (int j0 = 0; j0 < N_; j0 += 64) {
        float4 pj = pos4[j0 + lane];
        float dx = xi - pj.x;
        float dy = yi - pj.y;
        float dz = zi - pj.z;
        float r2 = fmaf(dx, dx, fmaf(dy, dy, dz * dz));
        unsigned long long mask = __ballot(r2 < TH2);

        while (mask) {
            int src = __builtin_ctzll(mask);
            mask &= mask - 1;
            // broadcast candidate delta (uniform src -> readlane)
            float cdx = __shfl(dx, src);
            float cdy = __shfl(dy, src);
            float cdz = __shfl(dz, src);
            float cr2 = __shfl(r2, src);
            int   j   = j0 + src;

            // each lane computes w for cell k = lane:
            // d_k^2 = r^2 + 0.1*(e . delta) + 0.0025*|e|^2
            float m  = exf * cdx;
            m        = fmaf(eyf, cdy, m);
            m        = fmaf(ezf, cdz, m);
            float d2 = fmaf(0.1f, m, cr2) + nsq;
            float q2 = d2 * 100.0f;          // q^2 = (d/h)^2, h = 0.1
            float q  = sqrtf(q2);
            float w1 = fmaf(q2, fmaf(6.0f, q, -6.0f), 1.0f);   // 1 - 6q^2 + 6q^3
            float u  = 1.0f - q;
            float w2 = 2.0f * u * u * u;
            float w  = (q <= 0.5f) ? w1 : w2;
            w        = (q < 1.0f) ? w * SIGMA : 0.0f;          // NaN-safe (d2<0 rounding -> 0)

            float cf = coefb[j * C_ + c];    // 128B broadcast load, L2-hot

#pragma unroll
            for (int t = 0; t < 14; ++t) {
                float wt = __shfl(w, kbase + t);   // ds_bpermute, cells kbase..kbase+13
                acc[t] = fmaf(wt, cf, acc[t]);
            }
        }
    }

    float* frow = field + (size_t)qi * FDIM;
#pragma unroll
    for (int t = 0; t < 14; ++t) {
        frow[(kbase + t) * 32 + c] = acc[t];   // covers k = 0..27 (k=27 row is zeros)
    }
}

// ---------------- K3: epilogue — out = bias + FIELD(8192x896) . W2(896x32) --------------------
__global__ void __launch_bounds__(256) out_kernel(const float* __restrict__ field,
                                                  const float* __restrict__ W2,
                                                  const float* __restrict__ bias,
                                                  float* __restrict__ out) {
    int t  = blockIdx.x * 256 + threadIdx.x;   // t = qi*32 + o
    int o  = t & 31;
    int qi = t >> 5;
    const float* fr = field + (size_t)qi * FDIM;
    float s = bias[o];
#pragma unroll 4
    for (int f = 0; f < FDIM; ++f) {
        s = fmaf(fr[f], W2[f * 32 + o], s);
    }
    out[t] = s;
}

extern "C" void kernel_launch(void* const* d_in, const int* in_sizes, int n_in,
                              void* d_out, int out_size, void* d_ws, size_t ws_size,
                              hipStream_t stream) {
    const float* locs    = (const float*)d_in[0];
    const float* data    = (const float*)d_in[1];
    const float* density = (const float*)d_in[2];
    const float* weight  = (const float*)d_in[3];
    const float* bias    = (const float*)d_in[4];
    float* out = (float*)d_out;

    float* ws    = (float*)d_ws;
    float* coef  = ws;                                   // B*N*C      = 262144 f
    float* W2    = ws + (size_t)B_ * N_ * C_;            // FDIM*O     = 28672 f
    float* field = W2 + (size_t)FDIM * O_;               // B*N*FDIM   = 7340032 f (~29.4MB)

    // K1: 262144 + 28672 = 290816 threads = 1136 * 256
    prep_kernel<<<dim3(1136), dim3(256), 0, stream>>>(locs, data, density, weight, coef, W2);

    // K2: wave per query, 4 queries/block
    field_kernel<<<dim3((B_ * N_) / 4), dim3(256), 0, stream>>>(locs, coef, field);

    // K3: thread per (qi, o)
    out_kernel<<<dim3((B_ * N_ * O_) / 256), dim3(256), 0, stream>>>(field, W2, bias, out);
}

// Round 2
// 192.538 us; speedup vs baseline: 1.2127x; 1.2127x over previous
//
#include <hip/hip_runtime.h>
#include <hip/hip_bf16.h>

#define B_ 2
#define N_ 4096
#define C_ 32
#define O_ 32
#define NCELLS 27
#define FK 27              // stored cells
#define FDIM (FK * C_)     // 864
#define CAP 256            // candidate queue capacity per wave

constexpr float SIGMA = 2546.4790894703255f;   // 8/(pi*h^3), h=0.1
constexpr float TH2   = 0.0348215f;            // (0.1 + 0.05*sqrt(3))^2 + margin

// ---------------- K1: prep — coef = data/(invmass*density); W2[(k*32+c)*32+o] ----------------
__global__ void __launch_bounds__(256) prep_kernel(const float* __restrict__ locs,
                                                   const float* __restrict__ data,
                                                   const float* __restrict__ density,
                                                   const float* __restrict__ weight,
                                                   float* __restrict__ coef,
                                                   float* __restrict__ W2) {
    int t = blockIdx.x * 256 + threadIdx.x;
    if (t < B_ * N_ * C_) {
        int bj = t >> 5;                       // b*N + j   (C_ == 32)
        float im = locs[bj * 4 + 3];           // invmass lives in locs[...,3]
        float de = density[bj];
        coef[t] = data[t] * (1.0f / (im * de));
    } else {
        int u = t - B_ * N_ * C_;
        if (u < FDIM * O_) {
            int o = u & 31;
            int f = u >> 5;                    // f = k*32 + c, f < 864 -> k < 27
            int k = f >> 5;
            int c = f & 31;
            W2[u] = weight[(o * C_ + c) * NCELLS + k];
        }
    }
}

// ---------------- K2: per-wave query; LDS candidate queue; lane = (cell, 16-ch half) ---------
__global__ void __launch_bounds__(256) field_kernel(const float* __restrict__ locs,
                                                    const float* __restrict__ coef,
                                                    float* __restrict__ field) {
    __shared__ float4 candbuf[4][CAP];         // 16 KB

    const int wave = threadIdx.x >> 6;
    const int lane = threadIdx.x & 63;
    const int qi   = blockIdx.x * 4 + wave;    // 0..8191
    const int b    = qi >> 12;
    const int i    = qi & (N_ - 1);

    const float4* pos4 = reinterpret_cast<const float4*>(locs) + (size_t)b * N_;
    float4 pq = pos4[i];
    const float xi = pq.x, yi = pq.y, zi = pq.z;

    // lane owns cell k = lane&31 (k>=27 -> dead, forced w=0); half h owns channels h*16..+15
    const int k = lane & 31;
    const int h = lane >> 6 ? 0 : (lane >> 5);     // = lane>>5
    const float exf = (float)(k / 9)       - 1.0f;
    const float eyf = (float)((k / 3) % 3) - 1.0f;
    const float ezf = (float)(k % 3)       - 1.0f;
    const float nsq = (k < NCELLS)
        ? 0.0025f * (exf * exf + eyf * eyf + ezf * ezf)
        : 1e9f;                                    // dead lane -> q>=1 -> w=0

    const float* cb = coef + (size_t)b * N_ * C_ + (h << 4);   // + h*16 channels

    float acc[16];
#pragma unroll
    for (int t = 0; t < 16; ++t) acc[t] = 0.0f;

    const unsigned long long lanemask = (1ull << lane) - 1ull;
    int count = 0;

    float4* myq = candbuf[wave];

    auto flush = [&](int cnt) {
        asm volatile("s_waitcnt lgkmcnt(0)" ::: "memory");   // LDS writes visible wave-wide
        for (int t = 0; t < cnt; ++t) {
            float4 cd = myq[t];                  // same addr all lanes -> broadcast read
            float dx = cd.x, dy = cd.y, dz = cd.z;
            int   j  = __float_as_int(cd.w);
            float r2 = fmaf(dx, dx, fmaf(dy, dy, dz * dz));
            float m  = fmaf(ezf, dz, fmaf(eyf, dy, exf * dx));
            float d2 = fmaf(0.1f, m, r2) + nsq;
            float q2 = d2 * 100.0f;
            float q  = sqrtf(q2);
            float w1 = fmaf(q2, fmaf(6.0f, q, -6.0f), 1.0f); // 1 - 6q^2 + 6q^3
            float u  = 1.0f - q;
            float w2 = 2.0f * u * u * u;
            float w  = (q <= 0.5f) ? w1 : w2;
            w        = (q < 1.0f) ? w * SIGMA : 0.0f;        // NaN-safe

            const float4* cr = reinterpret_cast<const float4*>(cb + (size_t)j * C_);
            float4 c0 = cr[0], c1 = cr[1], c2 = cr[2], c3 = cr[3];
            acc[0]  = fmaf(w, c0.x, acc[0]);
            acc[1]  = fmaf(w, c0.y, acc[1]);
            acc[2]  = fmaf(w, c0.z, acc[2]);
            acc[3]  = fmaf(w, c0.w, acc[3]);
            acc[4]  = fmaf(w, c1.x, acc[4]);
            acc[5]  = fmaf(w, c1.y, acc[5]);
            acc[6]  = fmaf(w, c1.z, acc[6]);
            acc[7]  = fmaf(w, c1.w, acc[7]);
            acc[8]  = fmaf(w, c2.x, acc[8]);
            acc[9]  = fmaf(w, c2.y, acc[9]);
            acc[10] = fmaf(w, c2.z, acc[10]);
            acc[11] = fmaf(w, c2.w, acc[11]);
            acc[12] = fmaf(w, c3.x, acc[12]);
            acc[13] = fmaf(w, c3.y, acc[13]);
            acc[14] = fmaf(w, c3.z, acc[14]);
            acc[15] = fmaf(w, c3.w, acc[15]);
        }
    };

    for (int j0 = 0; j0 < N_; j0 += 64) {
        float4 pj = pos4[j0 + lane];
        float dx = xi - pj.x;
        float dy = yi - pj.y;
        float dz = zi - pj.z;
        float r2 = fmaf(dx, dx, fmaf(dy, dy, dz * dz));
        bool hit = r2 < TH2;
        unsigned long long mask = __ballot(hit);
        if (hit) {
            int pos = count + __popcll(mask & lanemask);
            myq[pos] = make_float4(dx, dy, dz, __int_as_float(j0 + lane));
        }
        count += __popcll(mask);
        if (count > CAP - 64) {                  // guarantee room for next chunk
            flush(count);
            count = 0;
        }
    }
    flush(count);

    // write field: lane's cell k, channels h*16..h*16+15
    if (k < FK) {
        float* frow = field + (size_t)qi * FDIM + k * C_ + (h << 4);
        reinterpret_cast<float4*>(frow)[0] = make_float4(acc[0],  acc[1],  acc[2],  acc[3]);
        reinterpret_cast<float4*>(frow)[1] = make_float4(acc[4],  acc[5],  acc[6],  acc[7]);
        reinterpret_cast<float4*>(frow)[2] = make_float4(acc[8],  acc[9],  acc[10], acc[11]);
        reinterpret_cast<float4*>(frow)[3] = make_float4(acc[12], acc[13], acc[14], acc[15]);
    }
}

// ---------------- K3: out = bias + FIELD(8192x864) . W2(864x32), 4 partial chains ------------
__global__ void __launch_bounds__(256) out_kernel(const float* __restrict__ field,
                                                  const float* __restrict__ W2,
                                                  const float* __restrict__ bias,
                                                  float* __restrict__ out) {
    int t  = blockIdx.x * 256 + threadIdx.x;   // t = qi*32 + o
    int o  = t & 31;
    int qi = t >> 5;
    const float* fr = field + (size_t)qi * FDIM;
    float s0 = 0.f, s1 = 0.f, s2 = 0.f, s3 = 0.f;
#pragma unroll 8
    for (int f = 0; f < FDIM; f += 4) {
        s0 = fmaf(fr[f + 0], W2[(f + 0) * 32 + o], s0);
        s1 = fmaf(fr[f + 1], W2[(f + 1) * 32 + o], s1);
        s2 = fmaf(fr[f + 2], W2[(f + 2) * 32 + o], s2);
        s3 = fmaf(fr[f + 3], W2[(f + 3) * 32 + o], s3);
    }
    out[t] = bias[o] + ((s0 + s1) + (s2 + s3));
}

extern "C" void kernel_launch(void* const* d_in, const int* in_sizes, int n_in,
                              void* d_out, int out_size, void* d_ws, size_t ws_size,
                              hipStream_t stream) {
    const float* locs    = (const float*)d_in[0];
    const float* data    = (const float*)d_in[1];
    const float* density = (const float*)d_in[2];
    const float* weight  = (const float*)d_in[3];
    const float* bias    = (const float*)d_in[4];
    float* out = (float*)d_out;

    float* ws    = (float*)d_ws;
    float* coef  = ws;                                   // B*N*C   = 262144 f
    float* W2    = ws + (size_t)B_ * N_ * C_;            // 864*32  = 27648 f
    float* field = W2 + (size_t)FDIM * O_;               // 8192*864 = 7077888 f (~28.3MB)

    // K1: 262144 + 27648 = 289792 threads = 1132 * 256
    prep_kernel<<<dim3(1132), dim3(256), 0, stream>>>(locs, data, density, weight, coef, W2);

    // K2: wave per query, 4 queries/block
    field_kernel<<<dim3((B_ * N_) / 4), dim3(256), 0, stream>>>(locs, coef, field);

    // K3: thread per (qi, o)
    out_kernel<<<dim3((B_ * N_ * O_) / 256), dim3(256), 0, stream>>>(field, W2, bias, out);
}

// Round 3
// 102.179 us; speedup vs baseline: 2.2850x; 1.8843x over previous
//
#include <hip/hip_runtime.h>
#include <hip/hip_bf16.h>

#define B_ 2
#define N_ 4096
#define C_ 32
#define O_ 32
#define NCELLS 27
#define FDIM (NCELLS * C_)   // 864
#define CAP 256

typedef __attribute__((ext_vector_type(16))) float f32x16;
typedef __attribute__((ext_vector_type(4)))  float f32x4;
typedef __attribute__((ext_vector_type(8)))  short bf16x8;

constexpr float SIGMA = 2546.4790894703255f;   // 8/(pi*h^3), h=0.1
constexpr float TH2   = 0.0348215f;            // (0.1 + 0.05*sqrt(3))^2 + margin

__device__ __forceinline__ unsigned short bf16_rne(float f) {
    unsigned u = __float_as_uint(f);
    u += 0x7fffu + ((u >> 16) & 1u);
    return (unsigned short)(u >> 16);
}
__device__ __forceinline__ float bf16_to_f32(unsigned short h) {
    unsigned u = ((unsigned)h) << 16;
    return __uint_as_float(u);
}

// ---- K1: coefh = bf16(data/(invmass*density)); W2 pre-swizzled into 16x16x32 B-frag order ----
// W2frag[nt][kc][lane][b] (hi and lo): B[k][o] with k = kc*32 + (lane>>4)*8 + b  (k = f = cell*32+c),
// o = nt*16 + (lane&15).
__global__ void __launch_bounds__(256) prep_kernel(const float* __restrict__ locs,
                                                   const float* __restrict__ data,
                                                   const float* __restrict__ density,
                                                   const float* __restrict__ weight,
                                                   unsigned short* __restrict__ coefh,
                                                   unsigned short* __restrict__ W2fh,
                                                   unsigned short* __restrict__ W2fl) {
    int t = blockIdx.x * 256 + threadIdx.x;
    if (t < B_ * N_ * C_) {
        int bj = t >> 5;                       // b*N + j
        float im = locs[bj * 4 + 3];
        float de = density[bj];
        float c = data[t] * (1.0f / (im * de));
        coefh[t] = bf16_rne(c);
    } else {
        int u = t - B_ * N_ * C_;
        if (u < 2 * 27 * 64 * 8) {             // 2 ntiles * 27 kc * 64 lanes * 8 regs = 27648
            int b    = u & 7;
            int l    = (u >> 3) & 63;
            int rest = u >> 9;                 // 0..53
            int kc   = rest % 27;
            int nt   = rest / 27;
            int f    = kc * 32 + ((l >> 4) & 3) * 8 + b;   // < 864
            int m    = f >> 5;                 // cell
            int n    = f & 31;                 // channel
            int o    = nt * 16 + (l & 15);
            float wv = weight[(o * C_ + n) * NCELLS + m];
            unsigned short hi = bf16_rne(wv);
            float rem = wv - bf16_to_f32(hi);
            W2fh[u] = hi;
            W2fl[u] = bf16_rne(rem);
        }
    }
}

// ---- K2: per-wave query; LDS candidate queue; MFMA 32x32x16 (M=cells, N=channels, K=cands) ----
__global__ void __launch_bounds__(256) field_kernel(const float* __restrict__ locs,
                                                    const unsigned short* __restrict__ coefh,
                                                    float* __restrict__ field) {
    __shared__ float4 candbuf[4][CAP];         // 16 KB

    const int wave = threadIdx.x >> 6;
    const int lane = threadIdx.x & 63;
    const int qi   = blockIdx.x * 4 + wave;    // 0..8191
    const int bi   = qi >> 12;
    const int i    = qi & (N_ - 1);

    const float4* pos4 = reinterpret_cast<const float4*>(locs) + (size_t)bi * N_;
    float4 pq = pos4[i];
    const float xi = pq.x, yi = pq.y, zi = pq.z;

    // lane owns cell m = lane&31 (m>=27 dead -> w=0 via nsq); k-group h = lane>>5
    const int m32 = lane & 31;
    const int h   = lane >> 5;
    const float exf = (float)(m32 / 9)       - 1.0f;
    const float eyf = (float)((m32 / 3) % 3) - 1.0f;
    const float ezf = (float)(m32 % 3)       - 1.0f;
    const float nsq = (m32 < NCELLS)
        ? 0.0025f * (exf * exf + eyf * eyf + ezf * ezf)
        : 1e9f;

    const unsigned short* cb = coefh + (size_t)bi * N_ * C_ + m32;  // + channel n = lane&31

    f32x16 acc;
#pragma unroll
    for (int r = 0; r < 16; ++r) acc[r] = 0.0f;

    const unsigned long long lanemask = (1ull << lane) - 1ull;
    int count = 0;
    float4* myq = candbuf[wave];

    auto flush = [&](int cnt) {
        asm volatile("s_waitcnt lgkmcnt(0)" ::: "memory");   // wave's LDS writes visible
        int nb = (cnt + 15) >> 4;
        for (int bt = 0; bt < nb; ++bt) {
            int base = bt * 16 + h * 8;
            bf16x8 aF, bF;
#pragma unroll
            for (int b = 0; b < 8; ++b) {
                int t      = base + b;
                bool valid = t < cnt;
                float4 cd  = myq[t];           // 2 addrs per wave -> broadcast read
                float dx = cd.x, dy = cd.y, dz = cd.z;
                int jraw = __float_as_int(cd.w);
                int jc   = valid ? jraw : 0;
                float r2 = fmaf(dx, dx, fmaf(dy, dy, dz * dz));
                float mm = fmaf(ezf, dz, fmaf(eyf, dy, exf * dx));
                float d2 = fmaf(0.1f, mm, r2) + nsq;
                d2       = valid ? d2 : 1e9f;
                float q2 = d2 * 100.0f;
                float q  = sqrtf(q2);
                float w1 = fmaf(q2, fmaf(6.0f, q, -6.0f), 1.0f);
                float u1 = 1.0f - q;
                float w2 = 2.0f * u1 * u1 * u1;
                float w  = (q <= 0.5f) ? w1 : w2;
                w        = (q < 1.0f) ? w * SIGMA : 0.0f;    // NaN/garbage-safe
                aF[b] = (short)bf16_rne(w);
                bF[b] = (short)cb[jc * C_];    // coef bf16 gather (64B/half-wave)
            }
            acc = __builtin_amdgcn_mfma_f32_32x32x16_bf16(aF, bF, acc, 0, 0, 0);
        }
    };

    for (int j0 = 0; j0 < N_; j0 += 64) {
        float4 pj = pos4[j0 + lane];
        float dx = xi - pj.x;
        float dy = yi - pj.y;
        float dz = zi - pj.z;
        float r2 = fmaf(dx, dx, fmaf(dy, dy, dz * dz));
        bool hit = r2 < TH2;
        unsigned long long mask = __ballot(hit);
        if (hit) {
            int pos = count + __popcll(mask & lanemask);
            myq[pos] = make_float4(dx, dy, dz, __int_as_float(j0 + lane));
        }
        count += __popcll(mask);
        if (count > CAP - 64) {
            flush(count);
            count = 0;
        }
    }
    flush(count);

    // C/D layout (verified): row m = (r&3) + 8*(r>>2) + 4*h, col n = lane&31
    float* frow = field + (size_t)qi * FDIM;
#pragma unroll
    for (int r = 0; r < 16; ++r) {
        int m = (r & 3) + 8 * (r >> 2) + 4 * h;
        if (m < NCELLS) frow[m * 32 + m32] = acc[r];
    }
}

// ---- K3: out = bias + FIELD(8192x864) . W2(864x32) via 16x16x32 MFMA, fp32->bf16 hi/lo ----
__global__ void __launch_bounds__(256) out_kernel(const float* __restrict__ field,
                                                  const unsigned short* __restrict__ W2fh,
                                                  const unsigned short* __restrict__ W2fl,
                                                  const float* __restrict__ bias,
                                                  float* __restrict__ out) {
    const int wave = threadIdx.x >> 6;
    const int lane = threadIdx.x & 63;
    const int wid  = blockIdx.x * 4 + wave;    // 0..511
    const int row0 = wid * 16;
    const int arow = row0 + (lane & 15);       // A row (query)
    const int kg   = (lane >> 4) & 3;          // k-group

    const bf16x8* Bh = reinterpret_cast<const bf16x8*>(W2fh);
    const bf16x8* Bl = reinterpret_cast<const bf16x8*>(W2fl);

    f32x4 acc0, acc1;
#pragma unroll
    for (int r = 0; r < 4; ++r) { acc0[r] = 0.0f; acc1[r] = 0.0f; }

    const float* fr = field + (size_t)arow * FDIM;

    for (int kc = 0; kc < 27; ++kc) {
        int k0 = kc * 32 + kg * 8;
        float4 f0 = *reinterpret_cast<const float4*>(fr + k0);
        float4 f1 = *reinterpret_cast<const float4*>(fr + k0 + 4);
        float fv[8] = {f0.x, f0.y, f0.z, f0.w, f1.x, f1.y, f1.z, f1.w};
        bf16x8 ah, al;
#pragma unroll
        for (int b = 0; b < 8; ++b) {
            unsigned short hi = bf16_rne(fv[b]);
            ah[b] = (short)hi;
            al[b] = (short)bf16_rne(fv[b] - bf16_to_f32(hi));
        }
        bf16x8 bh0 = Bh[(0 * 27 + kc) * 64 + lane];
        bf16x8 bl0 = Bl[(0 * 27 + kc) * 64 + lane];
        bf16x8 bh1 = Bh[(1 * 27 + kc) * 64 + lane];
        bf16x8 bl1 = Bl[(1 * 27 + kc) * 64 + lane];
        acc0 = __builtin_amdgcn_mfma_f32_16x16x32_bf16(ah, bh0, acc0, 0, 0, 0);
        acc0 = __builtin_amdgcn_mfma_f32_16x16x32_bf16(al, bh0, acc0, 0, 0, 0);
        acc0 = __builtin_amdgcn_mfma_f32_16x16x32_bf16(ah, bl0, acc0, 0, 0, 0);
        acc1 = __builtin_amdgcn_mfma_f32_16x16x32_bf16(ah, bh1, acc1, 0, 0, 0);
        acc1 = __builtin_amdgcn_mfma_f32_16x16x32_bf16(al, bh1, acc1, 0, 0, 0);
        acc1 = __builtin_amdgcn_mfma_f32_16x16x32_bf16(ah, bl1, acc1, 0, 0, 0);
    }

    // C/D layout (verified): col = lane&15, row = (lane>>4)*4 + r
    float b0 = bias[0 * 16 + (lane & 15)];
    float b1 = bias[1 * 16 + (lane & 15)];
#pragma unroll
    for (int r = 0; r < 4; ++r) {
        int orow = row0 + kg * 4 + r;
        out[(size_t)orow * O_ + 0 * 16 + (lane & 15)] = acc0[r] + b0;
        out[(size_t)orow * O_ + 1 * 16 + (lane & 15)] = acc1[r] + b1;
    }
}

extern "C" void kernel_launch(void* const* d_in, const int* in_sizes, int n_in,
                              void* d_out, int out_size, void* d_ws, size_t ws_size,
                              hipStream_t stream) {
    const float* locs    = (const float*)d_in[0];
    const float* data    = (const float*)d_in[1];
    const float* density = (const float*)d_in[2];
    const float* weight  = (const float*)d_in[3];
    const float* bias    = (const float*)d_in[4];
    float* out = (float*)d_out;

    float* field = (float*)d_ws;                                  // 8192*864 f = 28.3MB
    unsigned short* coefh = (unsigned short*)(field + (size_t)B_ * N_ * FDIM);  // 262144 u16
    unsigned short* W2fh  = coefh + (size_t)B_ * N_ * C_;         // 27648 u16
    unsigned short* W2fl  = W2fh + 27648;                         // 27648 u16

    // K1: 262144 + 27648 = 289792 threads = 1132 * 256
    prep_kernel<<<dim3(1132), dim3(256), 0, stream>>>(locs, data, density, weight,
                                                      coefh, W2fh, W2fl);

    // K2: wave per query, 4 queries/block
    field_kernel<<<dim3((B_ * N_) / 4), dim3(256), 0, stream>>>(locs, coefh, field);

    // K3: wave per 16 queries, 4 waves/block -> 128 blocks
    out_kernel<<<dim3(128), dim3(256), 0, stream>>>(field, W2fh, W2fl, bias, out);
}

// Round 6
// 73.879 us; speedup vs baseline: 3.1604x; 1.3831x over previous
//
#include <hip/hip_runtime.h>
#include <hip/hip_bf16.h>

#define B_ 2
#define N_ 4096
#define C_ 32
#define O_ 32
#define NCELLS 27
#define FDIM (NCELLS * C_)   // 864
#define CAP 256
#define G_ 5
#define NBIN 125             // per batch

typedef __attribute__((ext_vector_type(16))) float f32x16;
typedef __attribute__((ext_vector_type(4)))  float f32x4;
typedef __attribute__((ext_vector_type(8)))  short bf16x8;

constexpr float SIGMA = 2546.4790894703255f;   // 8/(pi*h^3), h=0.1
constexpr float SIG6  = 6.0f * SIGMA;
constexpr float SIG2  = 2.0f * SIGMA;
constexpr float RC2TH = 0.010001f;             // (rounded-cube dist)^2 < r^2, tiny margin

__device__ __forceinline__ unsigned short bf16_rne(float f) {
    unsigned u = __float_as_uint(f);
    u += 0x7fffu + ((u >> 16) & 1u);
    return (unsigned short)(u >> 16);
}
__device__ __forceinline__ float bf16_to_f32(unsigned short h) {
    return __uint_as_float(((unsigned)h) << 16);
}
__device__ __forceinline__ int bin1(float x) {
    int v = (int)(x * 5.0f);
    return v < 0 ? 0 : (v > 4 ? 4 : v);
}

// ---- K1: coefh; W2 hi/lo in 16x16x32 B-frag order; bin histogram ----
__global__ void __launch_bounds__(256) prep_kernel(const float* __restrict__ locs,
                                                   const float* __restrict__ data,
                                                   const float* __restrict__ density,
                                                   const float* __restrict__ weight,
                                                   unsigned short* __restrict__ coefh,
                                                   unsigned short* __restrict__ W2fh,
                                                   unsigned short* __restrict__ W2fl,
                                                   int* __restrict__ cnt) {
    int t = blockIdx.x * 256 + threadIdx.x;
    if (t < B_ * N_ * C_) {
        int bj = t >> 5;
        float im = locs[bj * 4 + 3];
        float de = density[bj];
        coefh[t] = bf16_rne(data[t] * (1.0f / (im * de)));
    } else if (t < B_ * N_ * C_ + 27648) {
        int u = t - B_ * N_ * C_;                 // 2 ntiles * 27 kc * 64 lanes * 8 regs
        int b    = u & 7;
        int l    = (u >> 3) & 63;
        int rest = u >> 9;
        int kc   = rest % 27;
        int nt   = rest / 27;
        int f    = kc * 32 + ((l >> 4) & 3) * 8 + b;
        int m    = f >> 5;
        int n    = f & 31;
        int o    = nt * 16 + (l & 15);
        float wv = weight[(o * C_ + n) * NCELLS + m];
        unsigned short hi = bf16_rne(wv);
        W2fh[u] = hi;
        W2fl[u] = bf16_rne(wv - bf16_to_f32(hi));
    } else {
        int v = t - (B_ * N_ * C_ + 27648);       // 0..8191: bin histogram
        if (v < B_ * N_) {
            const float4* pos4 = reinterpret_cast<const float4*>(locs);
            float4 p = pos4[v];
            int bidx = (v >> 12) * NBIN + (bin1(p.x) * G_ + bin1(p.y)) * G_ + bin1(p.z);
            atomicAdd(&cnt[bidx], 1);
        }
    }
}

// ---- K1b: exclusive prefix over 250 bins (1 wave) ----
__global__ void __launch_bounds__(64) scan_kernel(const int* __restrict__ cnt,
                                                  int* __restrict__ off) {
    int l = threadIdx.x;
    int c0 = cnt[4 * l + 0], c1 = cnt[4 * l + 1], c2 = cnt[4 * l + 2], c3 = cnt[4 * l + 3];
    int s01 = c0 + c1;
    int s = s01 + c2 + c3;
    int incl = s;
#pragma unroll
    for (int d = 1; d < 64; d <<= 1) {
        int tt = __shfl_up(incl, d);
        if (l >= d) incl += tt;
    }
    int excl = incl - s;
    off[4 * l + 0] = excl;
    off[4 * l + 1] = excl + c0;
    off[4 * l + 2] = excl + s01;
    off[4 * l + 3] = excl + s01 + c2;
}

// ---- K1c: scatter particles into bin-sorted order (pos + original index) ----
__global__ void __launch_bounds__(256) scatter_kernel(const float* __restrict__ locs,
                                                      const int* __restrict__ off,
                                                      int* __restrict__ wcnt,
                                                      float4* __restrict__ spos) {
    int v = blockIdx.x * 256 + threadIdx.x;       // 0..8191
    const float4* pos4 = reinterpret_cast<const float4*>(locs);
    float4 p = pos4[v];
    int bidx = (v >> 12) * NBIN + (bin1(p.x) * G_ + bin1(p.y)) * G_ + bin1(p.z);
    int r = atomicAdd(&wcnt[bidx], 1);
    int dst = off[bidx] + r;
    if (dst >= 0 && dst < B_ * N_)
        spos[dst] = make_float4(p.x, p.y, p.z, __int_as_float(v & (N_ - 1)));
}

// ---- K2: per-wave query; binned run scan; LDS queue; MFMA 32x32x16; bf16-plane output ----
__global__ void __launch_bounds__(256) field_kernel(const float* __restrict__ locs,
                                                    const float4* __restrict__ spos,
                                                    const int* __restrict__ off,
                                                    const unsigned short* __restrict__ coefh,
                                                    unsigned short* __restrict__ fieldh,
                                                    unsigned short* __restrict__ fieldl) {
    __shared__ float4 candbuf[4][CAP];            // 16 KB

    const int wave = threadIdx.x >> 6;
    const int lane = threadIdx.x & 63;
    const int qi   = blockIdx.x * 4 + wave;
    const int bi   = qi >> 12;
    const int i    = qi & (N_ - 1);

    const float4* pos4 = reinterpret_cast<const float4*>(locs) + (size_t)bi * N_;
    float4 pq = pos4[i];
    const float xi = pq.x, yi = pq.y, zi = pq.z;

    // lane owns cell m32 = lane&31; per-lane cell offset (dead lanes pushed far away)
    const int m32 = lane & 31;
    const int h   = lane >> 5;
    const float ox = (m32 < NCELLS) ? 0.05f * (float)((m32 / 9) - 1)       : 1e4f;
    const float oy = (m32 < NCELLS) ? 0.05f * (float)(((m32 / 3) % 3) - 1) : 1e4f;
    const float oz = (m32 < NCELLS) ? 0.05f * (float)((m32 % 3) - 1)       : 1e4f;

    const unsigned short* cb = coefh + (size_t)bi * N_ * C_ + m32;   // channel n = lane&31

    f32x16 acc;
#pragma unroll
    for (int r = 0; r < 16; ++r) acc[r] = 0.0f;

    const unsigned long long lanemask = (1ull << lane) - 1ull;
    int count = 0;
    float4* myq = candbuf[wave];

    auto flush = [&](int cnt_) {
        asm volatile("s_waitcnt lgkmcnt(0)" ::: "memory");
        int nb = (cnt_ + 15) >> 4;
        for (int bt = 0; bt < nb; ++bt) {
            int base = bt * 16 + h * 8;
            float wv[8];
            unsigned cf[8];
#pragma unroll
            for (int b = 0; b < 8; ++b) {
                int t = base + b;
                bool valid = t < cnt_;
                float4 cd = myq[t];               // uniform addr per half-wave -> broadcast
                float tx = cd.x + ox;
                float ty = cd.y + oy;
                float tz = cd.z + oz;
                float d2 = fmaf(tz, tz, fmaf(ty, ty, tx * tx));   // >= 0 always
                d2 = valid ? d2 : 1e9f;           // stale-queue guard
                float q2 = d2 * 100.0f;
                float q  = __builtin_amdgcn_sqrtf(q2);
                float w1 = fmaf(q2, fmaf(SIG6, q, -SIG6), SIGMA); // sigma*(1-6q^2+6q^3)
                float u1 = 1.0f - q;
                float w2 = (SIG2 * u1) * (u1 * u1);               // <=0 for q>=1
                wv[b] = (q <= 0.5f) ? w1 : fmaxf(w2, 0.0f);
                int jc = valid ? __float_as_int(cd.w) : 0;
                cf[b] = (unsigned)cb[jc * C_];
            }
            union { bf16x8 v; unsigned u[4]; } aF, bF;
#pragma unroll
            for (int wg = 0; wg < 4; ++wg) {
                unsigned pk;
                asm("v_cvt_pk_bf16_f32 %0, %1, %2" : "=v"(pk)
                    : "v"(wv[2 * wg]), "v"(wv[2 * wg + 1]));
                aF.u[wg] = pk;
                bF.u[wg] = cf[2 * wg] | (cf[2 * wg + 1] << 16);
            }
            acc = __builtin_amdgcn_mfma_f32_32x32x16_bf16(aF.v, bF.v, acc, 0, 0, 0);
        }
    };

    // 9 z-runs of the 3x3x3 bin neighborhood; bounds fetched by lanes 0..8
    const int qbx = bin1(xi), qby = bin1(yi), qbz = bin1(zi);
    const int zlo = qbz > 0 ? qbz - 1 : 0;
    const int zhi = qbz < 4 ? qbz + 1 : 4;
    int rdx = lane / 3;
    int rdy = lane - rdx * 3;
    int bx = qbx + rdx - 1;
    int by = qby + rdy - 1;
    bool vv = (lane < 9) && (bx >= 0) && (bx < G_) && (by >= 0) && (by < G_);
    int bb = bi * NBIN + (bx * G_ + by) * G_;
    int vs0 = off[vv ? bb + zlo : 0];
    int vs1 = off[vv ? bb + zhi + 1 : 0];
    // defensive clamp: guarantee bounded loops even under corrupted workspace
    vs0 = vv ? (vs0 < 0 ? 0 : (vs0 > B_ * N_ ? B_ * N_ : vs0)) : 0;
    vs1 = vv ? (vs1 < vs0 ? vs0 : (vs1 > B_ * N_ ? B_ * N_ : vs1)) : 0;

    for (int r = 0; r < 9; ++r) {
        int rs = __shfl(vs0, r);
        int re = __shfl(vs1, r);
        for (int s = rs; s < re; s += 64) {
            int idx = s + lane;
            bool val = idx < re;
            float4 pj = spos[val ? idx : rs];
            float dx = xi - pj.x;
            float dy = yi - pj.y;
            float dz = zi - pj.z;
            // exact union-of-27-spheres test: sum max(|d|-0.05,0)^2 < 0.01
            float ax = fmaxf(fabsf(dx) - 0.05f, 0.0f);
            float ay = fmaxf(fabsf(dy) - 0.05f, 0.0f);
            float az = fmaxf(fabsf(dz) - 0.05f, 0.0f);
            float rc2 = fmaf(az, az, fmaf(ay, ay, ax * ax));
            bool hit = val && (rc2 < RC2TH);
            unsigned long long mask = __ballot(hit);
            if (hit) {
                int pos = count + __popcll(mask & lanemask);
                myq[pos] = make_float4(dx, dy, dz, pj.w);
            }
            count += __popcll(mask);
            if (count > CAP - 64) { flush(count); count = 0; }
        }
    }
    flush(count);

    // epilogue: f32 acc -> bf16 hi/lo planes.  C/D: row m=(r&3)+8*(r>>2)+4*h, col=lane&31
    unsigned short* fh = fieldh + (size_t)qi * FDIM + m32;
    unsigned short* fl = fieldl + (size_t)qi * FDIM + m32;
#pragma unroll
    for (int r = 0; r < 16; ++r) {
        int m = (r & 3) + 8 * (r >> 2) + 4 * h;
        if (m < NCELLS) {
            float f = acc[r];
            unsigned u = __float_as_uint(f);
            fh[m * 32] = (unsigned short)(u >> 16);                       // truncated hi
            fl[m * 32] = bf16_rne(f - __uint_as_float(u & 0xffff0000u));  // exact-ish lo
        }
    }
}

// ---- K3: out = bias + FIELD(8192x864) . W2(864x32), pure load+MFMA ----
__global__ void __launch_bounds__(64) out_kernel(const unsigned short* __restrict__ fieldh,
                                                 const unsigned short* __restrict__ fieldl,
                                                 const unsigned short* __restrict__ W2fh,
                                                 const unsigned short* __restrict__ W2fl,
                                                 const float* __restrict__ bias,
                                                 float* __restrict__ out) {
    const int lane = threadIdx.x;
    const int row0 = blockIdx.x * 16;
    const int arow = row0 + (lane & 15);
    const int kg   = lane >> 4;

    const bf16x8* Bh = reinterpret_cast<const bf16x8*>(W2fh);
    const bf16x8* Bl = reinterpret_cast<const bf16x8*>(W2fl);
    const unsigned short* fh = fieldh + (size_t)arow * FDIM;
    const unsigned short* fl = fieldl + (size_t)arow * FDIM;

    f32x4 acc0, acc1;
#pragma unroll
    for (int r = 0; r < 4; ++r) { acc0[r] = 0.0f; acc1[r] = 0.0f; }

    for (int kc = 0; kc < 27; ++kc) {
        int k0 = kc * 32 + kg * 8;
        bf16x8 ah = *reinterpret_cast<const bf16x8*>(fh + k0);
        bf16x8 al = *reinterpret_cast<const bf16x8*>(fl + k0);
        bf16x8 bh0 = Bh[kc * 64 + lane];
        bf16x8 bl0 = Bl[kc * 64 + lane];
        bf16x8 bh1 = Bh[(27 + kc) * 64 + lane];
        bf16x8 bl1 = Bl[(27 + kc) * 64 + lane];
        acc0 = __builtin_amdgcn_mfma_f32_16x16x32_bf16(ah, bh0, acc0, 0, 0, 0);
        acc0 = __builtin_amdgcn_mfma_f32_16x16x32_bf16(al, bh0, acc0, 0, 0, 0);
        acc0 = __builtin_amdgcn_mfma_f32_16x16x32_bf16(ah, bl0, acc0, 0, 0, 0);
        acc1 = __builtin_amdgcn_mfma_f32_16x16x32_bf16(ah, bh1, acc1, 0, 0, 0);
        acc1 = __builtin_amdgcn_mfma_f32_16x16x32_bf16(al, bh1, acc1, 0, 0, 0);
        acc1 = __builtin_amdgcn_mfma_f32_16x16x32_bf16(ah, bl1, acc1, 0, 0, 0);
    }

    int col = lane & 15;
    float b0 = bias[col];
    float b1 = bias[16 + col];
#pragma unroll
    for (int r = 0; r < 4; ++r) {
        int orow = row0 + kg * 4 + r;
        out[(size_t)orow * O_ + col]      = acc0[r] + b0;
        out[(size_t)orow * O_ + 16 + col] = acc1[r] + b1;
    }
}

extern "C" void kernel_launch(void* const* d_in, const int* in_sizes, int n_in,
                              void* d_out, int out_size, void* d_ws, size_t ws_size,
                              hipStream_t stream) {
    const float* locs    = (const float*)d_in[0];
    const float* data    = (const float*)d_in[1];
    const float* density = (const float*)d_in[2];
    const float* weight  = (const float*)d_in[3];
    const float* bias    = (const float*)d_in[4];
    float* out = (float*)d_out;

    char* base = (char*)d_ws;
    float4* spos          = (float4*)base;                                  // 8192*16B
    unsigned short* fieldh = (unsigned short*)(base + 131072);              // 8192*864 u16
    unsigned short* fieldl = fieldh + (size_t)B_ * N_ * FDIM;
    unsigned short* coefh  = fieldl + (size_t)B_ * N_ * FDIM;               // 262144 u16
    unsigned short* W2fh   = coefh + (size_t)B_ * N_ * C_;                  // 27648 u16
    unsigned short* W2fl   = W2fh + 27648;
    int* cnt  = (int*)(W2fl + 27648);                                       // 256 ints
    int* wcnt = cnt + 256;                                                  // 256 ints
    int* off  = wcnt + 256;                                                 // 257 ints

    hipMemsetAsync(cnt, 0, 2 * 256 * sizeof(int), stream);                  // cnt + wcnt

    // K1: coef (262144) + W2 (27648) + histogram (8192) = 297984 = 1164*256
    prep_kernel<<<dim3(1164), dim3(256), 0, stream>>>(locs, data, density, weight,
                                                      coefh, W2fh, W2fl, cnt);
    scan_kernel<<<dim3(1), dim3(64), 0, stream>>>(cnt, off);
    scatter_kernel<<<dim3(32), dim3(256), 0, stream>>>(locs, off, wcnt, spos);

    field_kernel<<<dim3((B_ * N_) / 4), dim3(256), 0, stream>>>(locs, spos, off, coefh,
                                                                fieldh, fieldl);

    out_kernel<<<dim3((B_ * N_) / 16), dim3(64), 0, stream>>>(fieldh, fieldl,
                                                              W2fh, W2fl, bias, out);
}

// Round 8
// 71.917 us; speedup vs baseline: 3.2466x; 1.0273x over previous
//
#include <hip/hip_runtime.h>
#include <hip/hip_bf16.h>

#define B_ 2
#define N_ 4096
#define C_ 32
#define O_ 32
#define NCELLS 27
#define FDIM (NCELLS * C_)   // 864
#define CAP 256
#define G_ 5
#define NBIN 125             // per batch

typedef __attribute__((ext_vector_type(16))) float f32x16;
typedef __attribute__((ext_vector_type(4)))  float f32x4;
typedef __attribute__((ext_vector_type(8)))  short bf16x8;

constexpr float SIGMA = 2546.4790894703255f;   // 8/(pi*h^3), h=0.1
constexpr float SIG6  = 6.0f * SIGMA;
constexpr float SIG2  = 2.0f * SIGMA;
constexpr float RC2TH = 0.010001f;             // (rounded-cube dist)^2 < r^2, tiny margin

__device__ __forceinline__ unsigned short bf16_rne(float f) {
    unsigned u = __float_as_uint(f);
    u += 0x7fffu + ((u >> 16) & 1u);
    return (unsigned short)(u >> 16);
}
__device__ __forceinline__ float bf16_to_f32(unsigned short h) {
    return __uint_as_float(((unsigned)h) << 16);
}
__device__ __forceinline__ int bin1(float x) {
    int v = (int)(x * 5.0f);
    return v < 0 ? 0 : (v > 4 ? 4 : v);
}

// ---- K0: zero bin counters (replaces hipMemsetAsync -> no fillBuffer node in graph) ----
__global__ void __launch_bounds__(256) zero_kernel(int* __restrict__ cnt) {
    cnt[threadIdx.x] = 0;
    cnt[256 + threadIdx.x] = 0;
}

// ---- K1: coefh; W2 hi/lo in 16x16x32 B-frag order; bin histogram ----
__global__ void __launch_bounds__(256) prep_kernel(const float* __restrict__ locs,
                                                   const float* __restrict__ data,
                                                   const float* __restrict__ density,
                                                   const float* __restrict__ weight,
                                                   unsigned short* __restrict__ coefh,
                                                   unsigned short* __restrict__ W2fh,
                                                   unsigned short* __restrict__ W2fl,
                                                   int* __restrict__ cnt) {
    int t = blockIdx.x * 256 + threadIdx.x;
    if (t < B_ * N_ * C_) {
        int bj = t >> 5;
        float im = locs[bj * 4 + 3];
        float de = density[bj];
        coefh[t] = bf16_rne(data[t] * (1.0f / (im * de)));
    } else if (t < B_ * N_ * C_ + 27648) {
        int u = t - B_ * N_ * C_;                 // 2 ntiles * 27 kc * 64 lanes * 8 regs
        int b    = u & 7;
        int l    = (u >> 3) & 63;
        int rest = u >> 9;
        int kc   = rest % 27;
        int nt   = rest / 27;
        int f    = kc * 32 + ((l >> 4) & 3) * 8 + b;
        int m    = f >> 5;
        int n    = f & 31;
        int o    = nt * 16 + (l & 15);
        float wv = weight[(o * C_ + n) * NCELLS + m];
        unsigned short hi = bf16_rne(wv);
        W2fh[u] = hi;
        W2fl[u] = bf16_rne(wv - bf16_to_f32(hi));
    } else {
        int v = t - (B_ * N_ * C_ + 27648);       // 0..8191: bin histogram
        if (v < B_ * N_) {
            const float4* pos4 = reinterpret_cast<const float4*>(locs);
            float4 p = pos4[v];
            int bidx = (v >> 12) * NBIN + (bin1(p.x) * G_ + bin1(p.y)) * G_ + bin1(p.z);
            atomicAdd(&cnt[bidx], 1);
        }
    }
}

// ---- K1b: exclusive prefix over 250 bins (1 wave) ----
__global__ void __launch_bounds__(64) scan_kernel(const int* __restrict__ cnt,
                                                  int* __restrict__ off) {
    int l = threadIdx.x;
    int c0 = cnt[4 * l + 0], c1 = cnt[4 * l + 1], c2 = cnt[4 * l + 2], c3 = cnt[4 * l + 3];
    int s01 = c0 + c1;
    int s = s01 + c2 + c3;
    int incl = s;
#pragma unroll
    for (int d = 1; d < 64; d <<= 1) {
        int tt = __shfl_up(incl, d);
        if (l >= d) incl += tt;
    }
    int excl = incl - s;
    off[4 * l + 0] = excl;
    off[4 * l + 1] = excl + c0;
    off[4 * l + 2] = excl + s01;
    off[4 * l + 3] = excl + s01 + c2;
}

// ---- K1c: scatter into bin-sorted order; .w carries j<<6 (coef row byte offset) ----
__global__ void __launch_bounds__(256) scatter_kernel(const float* __restrict__ locs,
                                                      const int* __restrict__ off,
                                                      int* __restrict__ wcnt,
                                                      float4* __restrict__ spos) {
    int v = blockIdx.x * 256 + threadIdx.x;       // 0..8191
    const float4* pos4 = reinterpret_cast<const float4*>(locs);
    float4 p = pos4[v];
    int bidx = (v >> 12) * NBIN + (bin1(p.x) * G_ + bin1(p.y)) * G_ + bin1(p.z);
    int r = atomicAdd(&wcnt[bidx], 1);
    int dst = off[bidx] + r;
    if (dst >= 0 && dst < B_ * N_)
        spos[dst] = make_float4(p.x, p.y, p.z, __int_as_float((v & (N_ - 1)) << 6));
}

// ---- K2: per-wave query; binned run scan; sentinel-padded LDS queue; MFMA 32x32x16 ----
__global__ void __launch_bounds__(256) field_kernel(const float* __restrict__ locs,
                                                    const float4* __restrict__ spos,
                                                    const int* __restrict__ off,
                                                    const unsigned short* __restrict__ coefh,
                                                    unsigned short* __restrict__ fieldh,
                                                    unsigned short* __restrict__ fieldl) {
    __shared__ float4 candbuf[4][CAP];            // 16 KB

    const int wave = threadIdx.x >> 6;
    const int lane = threadIdx.x & 63;
    const int qi   = blockIdx.x * 4 + wave;
    const int bi   = qi >> 12;
    const int i    = qi & (N_ - 1);

    const float4* pos4 = reinterpret_cast<const float4*>(locs) + (size_t)bi * N_;
    float4 pq = pos4[i];
    const float xi = pq.x, yi = pq.y, zi = pq.z;

    // lane owns cell m32 = lane&31; dead lanes (>=27) pushed far away -> w==0
    const int m32 = lane & 31;
    const int h   = lane >> 5;
    const float ox = (m32 < NCELLS) ? 0.05f * (float)((m32 / 9) - 1)       : 1e4f;
    const float oy = (m32 < NCELLS) ? 0.05f * (float)(((m32 / 3) % 3) - 1) : 1e4f;
    const float oz = (m32 < NCELLS) ? 0.05f * (float)((m32 % 3) - 1)       : 1e4f;

    const char* cb = (const char*)(coefh + (size_t)bi * N_ * C_ + m32);   // + j<<6 bytes

    f32x16 acc;
#pragma unroll
    for (int r = 0; r < 16; ++r) acc[r] = 0.0f;

    const unsigned long long lanemask = (1ull << lane) - 1ull;
    int count = 0;
    float4* myq = candbuf[wave];

    auto flush = [&](int cnt_) {
        // pad queue to a multiple of 16 with far-away sentinels (w -> 0, j -> 0)
        int pad = (16 - (cnt_ & 15)) & 15;
        if (lane < pad) myq[cnt_ + lane] = make_float4(1e4f, 1e4f, 1e4f, __int_as_float(0));
        asm volatile("s_waitcnt lgkmcnt(0)" ::: "memory");
        int nb = (cnt_ + 15) >> 4;
        for (int bt = 0; bt < nb; ++bt) {
            int base = bt * 16 + h * 8;
            float wv[8];
            unsigned cf[8];
#pragma unroll
            for (int b = 0; b < 8; ++b) {
                float4 cd = myq[base + b];        // uniform addr per half-wave -> broadcast
                float tx = cd.x + ox;
                float ty = cd.y + oy;
                float tz = cd.z + oz;
                float d2 = fmaf(tz, tz, fmaf(ty, ty, tx * tx));   // >= 0 always
                float q2 = d2 * 100.0f;
                float q  = __builtin_amdgcn_sqrtf(q2);
                float w1 = fmaf(q2, fmaf(SIG6, q, -SIG6), SIGMA); // sigma*(1-6q^2+6q^3)
                float u1 = 1.0f - q;
                float w2 = (SIG2 * u1) * (u1 * u1);               // <=0 for q>=1
                // w1-w2 = sigma*(2q-1)^3  =>  exact spline = max(min(w1,w2),0)
                wv[b] = fmaxf(fminf(w1, w2), 0.0f);
                cf[b] = *(const unsigned short*)(cb + __float_as_int(cd.w));
            }
            union { bf16x8 v; unsigned u[4]; } aF, bF;
#pragma unroll
            for (int wg = 0; wg < 4; ++wg) {
                unsigned pk;
                asm("v_cvt_pk_bf16_f32 %0, %1, %2" : "=v"(pk)
                    : "v"(wv[2 * wg]), "v"(wv[2 * wg + 1]));
                aF.u[wg] = pk;
                bF.u[wg] = cf[2 * wg] | (cf[2 * wg + 1] << 16);
            }
            acc = __builtin_amdgcn_mfma_f32_32x32x16_bf16(aF.v, bF.v, acc, 0, 0, 0);
        }
    };

    // 9 z-runs of the 3x3x3 bin neighborhood; bounds fetched by lanes 0..8
    const int qbx = bin1(xi), qby = bin1(yi), qbz = bin1(zi);
    const int zlo = qbz > 0 ? qbz - 1 : 0;
    const int zhi = qbz < 4 ? qbz + 1 : 4;
    int rdx = lane / 3;
    int rdy = lane - rdx * 3;
    int bx = qbx + rdx - 1;
    int by = qby + rdy - 1;
    bool vv = (lane < 9) && (bx >= 0) && (bx < G_) && (by >= 0) && (by < G_);
    int bb = bi * NBIN + (bx * G_ + by) * G_;
    int vs0 = off[vv ? bb + zlo : 0];
    int vs1 = off[vv ? bb + zhi + 1 : 0];
    // defensive clamp: guarantee bounded loops even under corrupted workspace
    vs0 = vv ? (vs0 < 0 ? 0 : (vs0 > B_ * N_ ? B_ * N_ : vs0)) : 0;
    vs1 = vv ? (vs1 < vs0 ? vs0 : (vs1 > B_ * N_ ? B_ * N_ : vs1)) : 0;

    for (int r = 0; r < 9; ++r) {
        int rs = __shfl(vs0, r);
        int re = __shfl(vs1, r);
        for (int s = rs; s < re; s += 64) {
            int idx = s + lane;
            bool val = idx < re;
            float4 pj = spos[val ? idx : rs];
            float dx = xi - pj.x;
            float dy = yi - pj.y;
            float dz = zi - pj.z;
            // exact union-of-27-spheres test: sum max(|d|-0.05,0)^2 < 0.01
            float ax = fmaxf(fabsf(dx) - 0.05f, 0.0f);
            float ay = fmaxf(fabsf(dy) - 0.05f, 0.0f);
            float az = fmaxf(fabsf(dz) - 0.05f, 0.0f);
            float rc2 = fmaf(az, az, fmaf(ay, ay, ax * ax));
            bool hit = val && (rc2 < RC2TH);
            unsigned long long mask = __ballot(hit);
            if (hit) {
                int pos = count + __popcll(mask & lanemask);
                myq[pos] = make_float4(dx, dy, dz, pj.w);
            }
            count += __popcll(mask);
            if (count > CAP - 64) { flush(count); count = 0; }
        }
    }
    flush(count);

    // epilogue: f32 acc -> bf16 hi/lo planes.  C/D: row m=(r&3)+8*(r>>2)+4*h, col=lane&31
    unsigned short* fh = fieldh + (size_t)qi * FDIM + m32;
    unsigned short* fl = fieldl + (size_t)qi * FDIM + m32;
#pragma unroll
    for (int r = 0; r < 16; ++r) {
        int m = (r & 3) + 8 * (r >> 2) + 4 * h;
        if (m < NCELLS) {
            float f = acc[r];
            unsigned u = __float_as_uint(f);
            fh[m * 32] = (unsigned short)(u >> 16);                       // truncated hi
            fl[m * 32] = bf16_rne(f - __uint_as_float(u & 0xffff0000u));  // exact-ish lo
        }
    }
}

// ---- K3: out = bias + FIELD(8192x864) . W2(864x32), pure load+MFMA ----
__global__ void __launch_bounds__(64) out_kernel(const unsigned short* __restrict__ fieldh,
                                                 const unsigned short* __restrict__ fieldl,
                                                 const unsigned short* __restrict__ W2fh,
                                                 const unsigned short* __restrict__ W2fl,
                                                 const float* __restrict__ bias,
                                                 float* __restrict__ out) {
    const int lane = threadIdx.x;
    const int row0 = blockIdx.x * 16;
    const int arow = row0 + (lane & 15);
    const int kg   = lane >> 4;

    const bf16x8* Bh = reinterpret_cast<const bf16x8*>(W2fh);
    const bf16x8* Bl = reinterpret_cast<const bf16x8*>(W2fl);
    const unsigned short* fh = fieldh + (size_t)arow * FDIM;
    const unsigned short* fl = fieldl + (size_t)arow * FDIM;

    f32x4 acc0, acc1;
#pragma unroll
    for (int r = 0; r < 4; ++r) { acc0[r] = 0.0f; acc1[r] = 0.0f; }

    for (int kc = 0; kc < 27; ++kc) {
        int k0 = kc * 32 + kg * 8;
        bf16x8 ah = *reinterpret_cast<const bf16x8*>(fh + k0);
        bf16x8 al = *reinterpret_cast<const bf16x8*>(fl + k0);
        bf16x8 bh0 = Bh[kc * 64 + lane];
        bf16x8 bl0 = Bl[kc * 64 + lane];
        bf16x8 bh1 = Bh[(27 + kc) * 64 + lane];
        bf16x8 bl1 = Bl[(27 + kc) * 64 + lane];
        acc0 = __builtin_amdgcn_mfma_f32_16x16x32_bf16(ah, bh0, acc0, 0, 0, 0);
        acc0 = __builtin_amdgcn_mfma_f32_16x16x32_bf16(al, bh0, acc0, 0, 0, 0);
        acc0 = __builtin_amdgcn_mfma_f32_16x16x32_bf16(ah, bl0, acc0, 0, 0, 0);
        acc1 = __builtin_amdgcn_mfma_f32_16x16x32_bf16(ah, bh1, acc1, 0, 0, 0);
        acc1 = __builtin_amdgcn_mfma_f32_16x16x32_bf16(al, bh1, acc1, 0, 0, 0);
        acc1 = __builtin_amdgcn_mfma_f32_16x16x32_bf16(ah, bl1, acc1, 0, 0, 0);
    }

    int col = lane & 15;
    float b0 = bias[col];
    float b1 = bias[16 + col];
#pragma unroll
    for (int r = 0; r < 4; ++r) {
        int orow = row0 + kg * 4 + r;
        out[(size_t)orow * O_ + col]      = acc0[r] + b0;
        out[(size_t)orow * O_ + 16 + col] = acc1[r] + b1;
    }
}

extern "C" void kernel_launch(void* const* d_in, const int* in_sizes, int n_in,
                              void* d_out, int out_size, void* d_ws, size_t ws_size,
                              hipStream_t stream) {
    const float* locs    = (const float*)d_in[0];
    const float* data    = (const float*)d_in[1];
    const float* density = (const float*)d_in[2];
    const float* weight  = (const float*)d_in[3];
    const float* bias    = (const float*)d_in[4];
    float* out = (float*)d_out;

    char* base = (char*)d_ws;
    float4* spos          = (float4*)base;                                  // 8192*16B
    unsigned short* fieldh = (unsigned short*)(base + 131072);              // 8192*864 u16
    unsigned short* fieldl = fieldh + (size_t)B_ * N_ * FDIM;
    unsigned short* coefh  = fieldl + (size_t)B_ * N_ * FDIM;               // 262144 u16
    unsigned short* W2fh   = coefh + (size_t)B_ * N_ * C_;                  // 27648 u16
    unsigned short* W2fl   = W2fh + 27648;
    int* cnt  = (int*)(W2fl + 27648);                                       // 256 ints
    int* wcnt = cnt + 256;                                                  // 256 ints
    int* off  = wcnt + 256;                                                 // 257 ints

    zero_kernel<<<dim3(1), dim3(256), 0, stream>>>(cnt);                    // cnt + wcnt

    // K1: coef (262144) + W2 (27648) + histogram (8192) = 297984 = 1164*256
    prep_kernel<<<dim3(1164), dim3(256), 0, stream>>>(locs, data, density, weight,
                                                      coefh, W2fh, W2fl, cnt);
    scan_kernel<<<dim3(1), dim3(64), 0, stream>>>(cnt, off);
    scatter_kernel<<<dim3(32), dim3(256), 0, stream>>>(locs, off, wcnt, spos);

    field_kernel<<<dim3((B_ * N_) / 4), dim3(256), 0, stream>>>(locs, spos, off, coefh,
                                                                fieldh, fieldl);

    out_kernel<<<dim3((B_ * N_) / 16), dim3(64), 0, stream>>>(fieldh, fieldl,
                                                              W2fh, W2fl, bias, out);
}

// Round 10
// 52.665 us; speedup vs baseline: 4.4333x; 1.3655x over previous
//
#include <hip/hip_runtime.h>
#include <hip/hip_bf16.h>

#define B_ 2
#define N_ 4096
#define C_ 32
#define O_ 32
#define NCELLS 27
#define FDIM (NCELLS * C_)   // 864
#define CAP 256
#define G_ 5
#define NBIN 125             // per batch

typedef __attribute__((ext_vector_type(16))) float f32x16;
typedef __attribute__((ext_vector_type(4)))  float f32x4;
typedef __attribute__((ext_vector_type(8)))  short bf16x8;

constexpr float SIGMA = 2546.4790894703255f;   // 8/(pi*h^3), h=0.1
constexpr float SIG6  = 6.0f * SIGMA;
constexpr float SIG2  = 2.0f * SIGMA;
constexpr float RC2TH = 0.010001f;             // (rounded-cube dist)^2 < r^2, tiny margin

__device__ __forceinline__ unsigned short bf16_rne(float f) {
    unsigned u = __float_as_uint(f);
    u += 0x7fffu + ((u >> 16) & 1u);
    return (unsigned short)(u >> 16);
}
__device__ __forceinline__ int bin1(float x) {
    int v = (int)(x * 5.0f);
    return v < 0 ? 0 : (v > 4 ? 4 : v);
}

// ---- K0: zero bin counters (kernel, not hipMemsetAsync -> no fill node in our graph) ----
__global__ void __launch_bounds__(256) zero_kernel(int* __restrict__ cnt) {
    cnt[threadIdx.x] = 0;
    cnt[256 + threadIdx.x] = 0;
}

// ---- K1: coefh bf16; W2 hi plane in 16x16x32 B-frag order; bin histogram ----
__global__ void __launch_bounds__(256) prep_kernel(const float* __restrict__ locs,
                                                   const float* __restrict__ data,
                                                   const float* __restrict__ density,
                                                   const float* __restrict__ weight,
                                                   unsigned short* __restrict__ coefh,
                                                   unsigned short* __restrict__ W2fh,
                                                   int* __restrict__ cnt) {
    int t = blockIdx.x * 256 + threadIdx.x;
    if (t < B_ * N_ * C_) {
        int bj = t >> 5;
        float im = locs[bj * 4 + 3];
        float de = density[bj];
        coefh[t] = bf16_rne(data[t] * (1.0f / (im * de)));
    } else if (t < B_ * N_ * C_ + 27648) {
        int u = t - B_ * N_ * C_;                 // 2 ntiles * 27 kc * 64 lanes * 8 regs
        int b    = u & 7;
        int l    = (u >> 3) & 63;
        int rest = u >> 9;
        int kc   = rest % 27;
        int nt   = rest / 27;
        int f    = kc * 32 + ((l >> 4) & 3) * 8 + b;
        int m    = f >> 5;
        int n    = f & 31;
        int o    = nt * 16 + (l & 15);
        W2fh[u] = bf16_rne(weight[(o * C_ + n) * NCELLS + m]);
    } else {
        int v = t - (B_ * N_ * C_ + 27648);       // 0..8191: bin histogram
        if (v < B_ * N_) {
            const float4* pos4 = reinterpret_cast<const float4*>(locs);
            float4 p = pos4[v];
            int bidx = (v >> 12) * NBIN + (bin1(p.x) * G_ + bin1(p.y)) * G_ + bin1(p.z);
            atomicAdd(&cnt[bidx], 1);
        }
    }
}

// ---- K1c: per-block prefix (wave 0) + scatter into bin-sorted order; off also to global ----
__global__ void __launch_bounds__(256) scatter_kernel(const float* __restrict__ locs,
                                                      const int* __restrict__ cnt,
                                                      int* __restrict__ wcnt,
                                                      int* __restrict__ off_g,
                                                      float4* __restrict__ spos) {
    __shared__ int soff[256];
    if (threadIdx.x < 64) {
        int l = threadIdx.x;
        int c0 = cnt[4 * l + 0], c1 = cnt[4 * l + 1], c2 = cnt[4 * l + 2], c3 = cnt[4 * l + 3];
        int s01 = c0 + c1;
        int s = s01 + c2 + c3;
        int incl = s;
#pragma unroll
        for (int d = 1; d < 64; d <<= 1) {
            int tt = __shfl_up(incl, d);
            if (l >= d) incl += tt;
        }
        int excl = incl - s;
        soff[4 * l + 0] = excl;
        soff[4 * l + 1] = excl + c0;
        soff[4 * l + 2] = excl + s01;
        soff[4 * l + 3] = excl + s01 + c2;
        off_g[4 * l + 0] = excl;                  // all blocks write identical values
        off_g[4 * l + 1] = excl + c0;
        off_g[4 * l + 2] = excl + s01;
        off_g[4 * l + 3] = excl + s01 + c2;
    }
    __syncthreads();
    int v = blockIdx.x * 256 + threadIdx.x;       // 0..8191
    const float4* pos4 = reinterpret_cast<const float4*>(locs);
    float4 p = pos4[v];
    int bidx = (v >> 12) * NBIN + (bin1(p.x) * G_ + bin1(p.y)) * G_ + bin1(p.z);
    int r = atomicAdd(&wcnt[bidx], 1);
    int dst = soff[bidx] + r;
    if (dst >= 0 && dst < B_ * N_)
        spos[dst] = make_float4(p.x, p.y, p.z, __int_as_float((v & (N_ - 1)) << 6));
}

// ---- K2: wave per SORTED query; binned run scan; sentinel-padded LDS queue; MFMA ----
__global__ void __launch_bounds__(256) field_kernel(const float4* __restrict__ spos,
                                                    const int* __restrict__ off,
                                                    const unsigned short* __restrict__ coefh,
                                                    unsigned short* __restrict__ fieldh) {
    __shared__ float4 candbuf[4][CAP];            // 16 KB

    const int wave = threadIdx.x >> 6;
    const int lane = threadIdx.x & 63;
    const int qi   = blockIdx.x * 4 + wave;       // SORTED slot; block's 4 queries co-binned
    const int bi   = qi >> 12;                    // batch (bins are batch-major)

    float4 pq = spos[qi];
    const float xi = pq.x, yi = pq.y, zi = pq.z;

    // lane owns cell m32 = lane&31; dead lanes (>=27) pushed far away -> w==0
    const int m32 = lane & 31;
    const int h   = lane >> 5;
    const float ox = (m32 < NCELLS) ? 0.05f * (float)((m32 / 9) - 1)       : 1e4f;
    const float oy = (m32 < NCELLS) ? 0.05f * (float)(((m32 / 3) % 3) - 1) : 1e4f;
    const float oz = (m32 < NCELLS) ? 0.05f * (float)((m32 % 3) - 1)       : 1e4f;

    const char* cb = (const char*)(coefh + (size_t)bi * N_ * C_ + m32);   // + j<<6 bytes

    f32x16 acc;
#pragma unroll
    for (int r = 0; r < 16; ++r) acc[r] = 0.0f;

    const unsigned long long lanemask = (1ull << lane) - 1ull;
    int count = 0;
    float4* myq = candbuf[wave];

    auto flush = [&](int cnt_) {
        // pad queue to a multiple of 16 with far-away sentinels (w -> 0, j -> 0)
        int pad = (16 - (cnt_ & 15)) & 15;
        if (lane < pad) myq[cnt_ + lane] = make_float4(1e4f, 1e4f, 1e4f, __int_as_float(0));
        asm volatile("s_waitcnt lgkmcnt(0)" ::: "memory");
        int nb = (cnt_ + 15) >> 4;
        for (int bt = 0; bt < nb; ++bt) {
            int base = bt * 16 + h * 8;
            float wv[8];
            unsigned cf[8];
#pragma unroll
            for (int b = 0; b < 8; ++b) {
                float4 cd = myq[base + b];        // uniform addr per half-wave -> broadcast
                float tx = cd.x + ox;
                float ty = cd.y + oy;
                float tz = cd.z + oz;
                float d2 = fmaf(tz, tz, fmaf(ty, ty, tx * tx));   // >= 0 always
                float q2 = d2 * 100.0f;
                float q  = __builtin_amdgcn_sqrtf(q2);
                float w1 = fmaf(q2, fmaf(SIG6, q, -SIG6), SIGMA); // sigma*(1-6q^2+6q^3)
                float u1 = 1.0f - q;
                float w2 = (SIG2 * u1) * (u1 * u1);               // <=0 for q>=1
                // w1-w2 = sigma*(2q-1)^3  =>  exact spline = max(min(w1,w2),0)
                wv[b] = fmaxf(fminf(w1, w2), 0.0f);
                cf[b] = *(const unsigned short*)(cb + __float_as_int(cd.w));
            }
            union { bf16x8 v; unsigned u[4]; } aF, bF;
#pragma unroll
            for (int wg = 0; wg < 4; ++wg) {
                unsigned pk;
                asm("v_cvt_pk_bf16_f32 %0, %1, %2" : "=v"(pk)
                    : "v"(wv[2 * wg]), "v"(wv[2 * wg + 1]));
                aF.u[wg] = pk;
                bF.u[wg] = cf[2 * wg] | (cf[2 * wg + 1] << 16);
            }
            acc = __builtin_amdgcn_mfma_f32_32x32x16_bf16(aF.v, bF.v, acc, 0, 0, 0);
        }
    };

    // 9 z-runs of the 3x3x3 bin neighborhood; bounds fetched by lanes 0..8
    const int qbx = bin1(xi), qby = bin1(yi), qbz = bin1(zi);
    const int zlo = qbz > 0 ? qbz - 1 : 0;
    const int zhi = qbz < 4 ? qbz + 1 : 4;
    int rdx = lane / 3;
    int rdy = lane - rdx * 3;
    int bx = qbx + rdx - 1;
    int by = qby + rdy - 1;
    bool vv = (lane < 9) && (bx >= 0) && (bx < G_) && (by >= 0) && (by < G_);
    int bb = bi * NBIN + (bx * G_ + by) * G_;
    int vs0 = off[vv ? bb + zlo : 0];
    int vs1 = off[vv ? bb + zhi + 1 : 0];
    // defensive clamp: guarantee bounded loops even under corrupted workspace
    vs0 = vv ? (vs0 < 0 ? 0 : (vs0 > B_ * N_ ? B_ * N_ : vs0)) : 0;
    vs1 = vv ? (vs1 < vs0 ? vs0 : (vs1 > B_ * N_ ? B_ * N_ : vs1)) : 0;

    for (int r = 0; r < 9; ++r) {
        int rs = __shfl(vs0, r);
        int re = __shfl(vs1, r);
        for (int s = rs; s < re; s += 64) {
            int idx = s + lane;
            bool val = idx < re;
            float4 pj = spos[val ? idx : rs];
            float dx = xi - pj.x;
            float dy = yi - pj.y;
            float dz = zi - pj.z;
            // exact union-of-27-spheres test: sum max(|d|-0.05,0)^2 < 0.01
            float ax = fmaxf(fabsf(dx) - 0.05f, 0.0f);
            float ay = fmaxf(fabsf(dy) - 0.05f, 0.0f);
            float az = fmaxf(fabsf(dz) - 0.05f, 0.0f);
            float rc2 = fmaf(az, az, fmaf(ay, ay, ax * ax));
            bool hit = val && (rc2 < RC2TH);
            unsigned long long mask = __ballot(hit);
            if (hit) {
                int pos = count + __popcll(mask & lanemask);
                myq[pos] = make_float4(dx, dy, dz, pj.w);
            }
            count += __popcll(mask);
            if (count > CAP - 64) { flush(count); count = 0; }
        }
    }
    flush(count);

    // epilogue: f32 acc -> single bf16 plane (row = sorted slot qi)
    // C/D: row m=(r&3)+8*(r>>2)+4*h, col=lane&31
    unsigned short* fh = fieldh + (size_t)qi * FDIM + m32;
#pragma unroll
    for (int r = 0; r < 16; ++r) {
        int m = (r & 3) + 8 * (r >> 2) + 4 * h;
        if (m < NCELLS) fh[m * 32] = bf16_rne(acc[r]);
    }
}

// ---- K3: out = bias + FIELD(8192x864,sorted) . W2(864x32); un-permute rows on store ----
__global__ void __launch_bounds__(64) out_kernel(const unsigned short* __restrict__ fieldh,
                                                 const unsigned short* __restrict__ W2fh,
                                                 const float4* __restrict__ spos,
                                                 const float* __restrict__ bias,
                                                 float* __restrict__ out) {
    const int lane = threadIdx.x;
    const int row0 = blockIdx.x * 16;             // sorted-row tile
    const int arow = row0 + (lane & 15);          // A row (sorted query slot)
    const int kg   = lane >> 4;

    const bf16x8* Bh = reinterpret_cast<const bf16x8*>(W2fh);
    const unsigned short* fh = fieldh + (size_t)arow * FDIM;

    f32x4 acc0, acc1;
#pragma unroll
    for (int r = 0; r < 4; ++r) { acc0[r] = 0.0f; acc1[r] = 0.0f; }

    for (int kc = 0; kc < 27; ++kc) {
        int k0 = kc * 32 + kg * 8;
        bf16x8 ah  = *reinterpret_cast<const bf16x8*>(fh + k0);
        bf16x8 bh0 = Bh[kc * 64 + lane];
        bf16x8 bh1 = Bh[(27 + kc) * 64 + lane];
        acc0 = __builtin_amdgcn_mfma_f32_16x16x32_bf16(ah, bh0, acc0, 0, 0, 0);
        acc1 = __builtin_amdgcn_mfma_f32_16x16x32_bf16(ah, bh1, acc1, 0, 0, 0);
    }

    int col = lane & 15;
    float b0 = bias[col];
    float b1 = bias[16 + col];
#pragma unroll
    for (int r = 0; r < 4; ++r) {
        int srow = row0 + kg * 4 + r;             // sorted slot of this output row
        int oj   = __float_as_int(spos[srow].w) >> 6;          // original index in batch
        int orow = (srow >= N_ ? N_ : 0) + oj;                  // + batch offset
        out[(size_t)orow * O_ + col]      = acc0[r] + b0;
        out[(size_t)orow * O_ + 16 + col] = acc1[r] + b1;
    }
}

extern "C" void kernel_launch(void* const* d_in, const int* in_sizes, int n_in,
                              void* d_out, int out_size, void* d_ws, size_t ws_size,
                              hipStream_t stream) {
    const float* locs    = (const float*)d_in[0];
    const float* data    = (const float*)d_in[1];
    const float* density = (const float*)d_in[2];
    const float* weight  = (const float*)d_in[3];
    const float* bias    = (const float*)d_in[4];
    float* out = (float*)d_out;

    char* base = (char*)d_ws;
    float4* spos           = (float4*)base;                                 // 8192*16B
    unsigned short* fieldh = (unsigned short*)(base + 131072);              // 8192*864 u16
    unsigned short* coefh  = fieldh + (size_t)B_ * N_ * FDIM;               // 262144 u16
    unsigned short* W2fh   = coefh + (size_t)B_ * N_ * C_;                  // 27648 u16
    int* cnt  = (int*)(W2fh + 27648);                                       // 256 ints
    int* wcnt = cnt + 256;                                                  // 256 ints
    int* off  = wcnt + 256;                                                 // 256 ints

    zero_kernel<<<dim3(1), dim3(256), 0, stream>>>(cnt);                    // cnt + wcnt

    // K1: coef (262144) + W2 (27648) + histogram (8192) = 297984 = 1164*256
    prep_kernel<<<dim3(1164), dim3(256), 0, stream>>>(locs, data, density, weight,
                                                      coefh, W2fh, cnt);

    scatter_kernel<<<dim3(32), dim3(256), 0, stream>>>(locs, cnt, wcnt, off, spos);

    field_kernel<<<dim3((B_ * N_) / 4), dim3(256), 0, stream>>>(spos, off, coefh, fieldh);

    out_kernel<<<dim3((B_ * N_) / 16), dim3(64), 0, stream>>>(fieldh, W2fh, spos,
                                                              bias, out);
}